// Round 1
// baseline (5056.161 us; speedup 1.0000x reference)
//
#include <hip/hip_runtime.h>
#include <hip/hip_bf16.h>

#define NN 50000
#define NE 800000
#define F 128     // input feature dim
#define HD 128    // output dim = H*DH
#define H 4
#define DH 32

// ---------- helpers ----------

// order-preserving float<->uint encoding for atomicMax on signed floats
__device__ __forceinline__ unsigned enc_f(float x) {
    unsigned b = __float_as_uint(x);
    return (b & 0x80000000u) ? ~b : (b | 0x80000000u);
}
__device__ __forceinline__ float dec_f(unsigned u) {
    return (u & 0x80000000u) ? __uint_as_float(u ^ 0x80000000u)
                             : __uint_as_float(~u);
}

__device__ __forceinline__ float mish_f(float x) {
    float sp = (x > 20.f) ? x : log1pf(expf(x));
    return x * tanhf(sp);
}

// round-to-nearest-even f32 -> bf16 (as uint16 in low bits)
__device__ __forceinline__ unsigned f32_to_bf16(float x) {
    unsigned u = __float_as_uint(x);
    u += 0x7FFFu + ((u >> 16) & 1u);
    return u >> 16;
}
__device__ __forceinline__ float bf16lo_to_f32(unsigned p) {
    return __uint_as_float((p & 0xFFFFu) << 16);
}
__device__ __forceinline__ float bf16hi_to_f32(unsigned p) {
    return __uint_as_float(p & 0xFFFF0000u);
}

// ---------- K1: node projection  Y[m, :] = X[m, :] @ W + b ----------
__global__ __launch_bounds__(256) void proj_kernel(
    const float* __restrict__ X, const float* __restrict__ W,
    const float* __restrict__ b, float* __restrict__ Y, int M)
{
    __shared__ float2 sW[F * 64];
    __shared__ float2 sB[64];
    const float2* Wv = (const float2*)W;
    for (int i = threadIdx.x; i < F * 64; i += 256) sW[i] = Wv[i];
    if (threadIdx.x < 64) sB[threadIdx.x] = ((const float2*)b)[threadIdx.x];
    __syncthreads();

    int lane = threadIdx.x & 63;
    int wid  = blockIdx.x * 4 + (threadIdx.x >> 6);
    int nw   = gridDim.x * 4;
    for (int row = wid; row < M; row += nw) {
        const float* x = X + (size_t)row * F;
        float x0 = x[lane], x1 = x[lane + 64];
        float2 acc = sB[lane];
        #pragma unroll
        for (int f = 0; f < 64; ++f) {
            float xv = __shfl(x0, f);
            float2 w2 = sW[f * 64 + lane];
            acc.x = fmaf(xv, w2.x, acc.x);
            acc.y = fmaf(xv, w2.y, acc.y);
        }
        #pragma unroll
        for (int f = 0; f < 64; ++f) {
            float xv = __shfl(x1, f);
            float2 w2 = sW[(64 + f) * 64 + lane];
            acc.x = fmaf(xv, w2.x, acc.x);
            acc.y = fmaf(xv, w2.y, acc.y);
        }
        ((float2*)(Y + (size_t)row * HD))[lane] = acc;
    }
}

// ---------- K3: edge pass 1: e_att, logits, segment max ----------
template <bool STORE_EA>
__global__ __launch_bounds__(256) void edge1_kernel(
    const float* __restrict__ edges, const float* __restrict__ We,
    const float* __restrict__ We_b, const float* __restrict__ attw,
    const float* __restrict__ attb,
    const int* __restrict__ senders, const int* __restrict__ receivers,
    const float* __restrict__ S, const float* __restrict__ R,
    float* __restrict__ logits, unsigned* __restrict__ segmax,
    unsigned* __restrict__ EA /* packed 2x bf16 */)
{
    __shared__ float2 sW[F * 64];
    __shared__ float2 sB[64];
    __shared__ float2 sAw[16];
    const float2* Wv = (const float2*)We;
    for (int i = threadIdx.x; i < F * 64; i += 256) sW[i] = Wv[i];
    if (threadIdx.x < 64) sB[threadIdx.x] = ((const float2*)We_b)[threadIdx.x];
    if (threadIdx.x < 16) sAw[threadIdx.x] = ((const float2*)attw)[threadIdx.x];
    __syncthreads();

    int lane = threadIdx.x & 63;
    int e = blockIdx.x * 4 + (threadIdx.x >> 6);
    if (e >= NE) return;

    const float* x = edges + (size_t)e * F;
    float x0 = x[lane], x1 = x[lane + 64];
    float2 acc = sB[lane];
    #pragma unroll
    for (int f = 0; f < 64; ++f) {
        float xv = __shfl(x0, f);
        float2 w2 = sW[f * 64 + lane];
        acc.x = fmaf(xv, w2.x, acc.x);
        acc.y = fmaf(xv, w2.y, acc.y);
    }
    #pragma unroll
    for (int f = 0; f < 64; ++f) {
        float xv = __shfl(x1, f);
        float2 w2 = sW[(64 + f) * 64 + lane];
        acc.x = fmaf(xv, w2.x, acc.x);
        acc.y = fmaf(xv, w2.y, acc.y);
    }

    int snd = senders[e];
    int rcv = receivers[e];
    float2 s2 = ((const float2*)(S + (size_t)snd * HD))[lane];
    float2 ea = make_float2(acc.x + s2.x, acc.y + s2.y);

    if (STORE_EA) {
        unsigned packed = f32_to_bf16(ea.x) | (f32_to_bf16(ea.y) << 16);
        EA[(size_t)e * 64 + lane] = packed;
    }

    float2 r2 = ((const float2*)(R + (size_t)rcv * HD))[lane];
    float2 aw = sAw[lane & 15];
    float part = mish_f(ea.x + r2.x) * aw.x + mish_f(ea.y + r2.y) * aw.y;
    part += __shfl_xor(part, 1);
    part += __shfl_xor(part, 2);
    part += __shfl_xor(part, 4);
    part += __shfl_xor(part, 8);
    if ((lane & 15) == 0) {
        int h = lane >> 4;
        float lg = part + attb[0];
        logits[(size_t)e * 4 + h] = lg;
        atomicMax(segmax + (size_t)rcv * 4 + h, enc_f(lg));
    }
}

// ---------- K4: exp + denom ----------
__global__ __launch_bounds__(256) void edge2_kernel(
    const int* __restrict__ receivers, float* __restrict__ logits,
    const unsigned* __restrict__ segmax, float* __restrict__ denom)
{
    int i = blockIdx.x * 256 + threadIdx.x;
    if (i >= NE * H) return;
    int e = i >> 2, h = i & 3;
    int rcv = receivers[e];
    float m = dec_f(segmax[(size_t)rcv * 4 + h]);
    float w = expf(logits[i] - m);
    logits[i] = w;
    atomicAdd(denom + (size_t)rcv * 4 + h, w);
}

// ---------- K5a: aggregate from stored bf16 e_att ----------
__global__ __launch_bounds__(256) void edge3_ea_kernel(
    const int* __restrict__ receivers, const float* __restrict__ wbuf,
    const float* __restrict__ denom, const unsigned* __restrict__ EA,
    float* __restrict__ out)
{
    int lane = threadIdx.x & 63;
    int e = blockIdx.x * 4 + (threadIdx.x >> 6);
    if (e >= NE) return;
    int rcv = receivers[e];
    int h = lane >> 4;
    float w  = wbuf[(size_t)e * 4 + h];
    float dn = denom[(size_t)rcv * 4 + h];
    float c = w / dn;
    unsigned p = EA[(size_t)e * 64 + lane];
    float a = bf16lo_to_f32(p), b = bf16hi_to_f32(p);
    float* dst = out + (size_t)rcv * HD + 2 * lane;
    atomicAdd(dst, c * a);
    atomicAdd(dst + 1, c * b);
}

// ---------- K5b: aggregate with e_att recompute (small-ws fallback) ----------
__global__ __launch_bounds__(256) void edge3_rc_kernel(
    const float* __restrict__ edges, const float* __restrict__ We,
    const float* __restrict__ We_b,
    const int* __restrict__ senders, const int* __restrict__ receivers,
    const float* __restrict__ S, const float* __restrict__ wbuf,
    const float* __restrict__ denom, float* __restrict__ out)
{
    __shared__ float2 sW[F * 64];
    __shared__ float2 sB[64];
    const float2* Wv = (const float2*)We;
    for (int i = threadIdx.x; i < F * 64; i += 256) sW[i] = Wv[i];
    if (threadIdx.x < 64) sB[threadIdx.x] = ((const float2*)We_b)[threadIdx.x];
    __syncthreads();

    int lane = threadIdx.x & 63;
    int e = blockIdx.x * 4 + (threadIdx.x >> 6);
    if (e >= NE) return;

    const float* x = edges + (size_t)e * F;
    float x0 = x[lane], x1 = x[lane + 64];
    float2 acc = sB[lane];
    #pragma unroll
    for (int f = 0; f < 64; ++f) {
        float xv = __shfl(x0, f);
        float2 w2 = sW[f * 64 + lane];
        acc.x = fmaf(xv, w2.x, acc.x);
        acc.y = fmaf(xv, w2.y, acc.y);
    }
    #pragma unroll
    for (int f = 0; f < 64; ++f) {
        float xv = __shfl(x1, f);
        float2 w2 = sW[(64 + f) * 64 + lane];
        acc.x = fmaf(xv, w2.x, acc.x);
        acc.y = fmaf(xv, w2.y, acc.y);
    }

    int snd = senders[e];
    int rcv = receivers[e];
    float2 s2 = ((const float2*)(S + (size_t)snd * HD))[lane];
    float2 ea = make_float2(acc.x + s2.x, acc.y + s2.y);

    int h = lane >> 4;
    float w  = wbuf[(size_t)e * 4 + h];
    float dn = denom[(size_t)rcv * 4 + h];
    float c = w / dn;
    float* dst = out + (size_t)rcv * HD + 2 * lane;
    atomicAdd(dst, c * ea.x);
    atomicAdd(dst + 1, c * ea.y);
}

// ---------- host ----------
extern "C" void kernel_launch(void* const* d_in, const int* in_sizes, int n_in,
                              void* d_out, int out_size, void* d_ws, size_t ws_size,
                              hipStream_t stream) {
    const float* nodes = (const float*)d_in[0];
    const float* edges = (const float*)d_in[1];
    const float* Ws_k  = (const float*)d_in[2];
    const float* Ws_b  = (const float*)d_in[3];
    const float* Wr_k  = (const float*)d_in[4];
    const float* Wr_b  = (const float*)d_in[5];
    const float* We_k  = (const float*)d_in[6];
    const float* We_b  = (const float*)d_in[7];
    const float* attw  = (const float*)d_in[8];
    const float* attb  = (const float*)d_in[9];
    const int* senders   = (const int*)d_in[10];
    const int* receivers = (const int*)d_in[11];
    float* out = (float*)d_out;

    char* ws = (char*)d_ws;
    // layout (bytes)
    const size_t S_OFF   = 0;                    // 50000*128*4 = 25,600,000
    const size_t R_OFF   = 25600000;             // + 25,600,000
    const size_t LG_OFF  = 51200000;             // logits/w: 800000*4*4 = 12,800,000
    const size_t SM_OFF  = 64000000;             // segmax: 800,000
    const size_t DN_OFF  = 64800000;             // denom:  800,000
    const size_t EA_OFF  = 65600000;             // e_att bf16: 204,800,000
    const size_t NEED_FULL = EA_OFF + (size_t)NE * 64 * 4;

    float*    S      = (float*)(ws + S_OFF);
    float*    R      = (float*)(ws + R_OFF);
    float*    logits = (float*)(ws + LG_OFF);
    unsigned* segmax = (unsigned*)(ws + SM_OFF);
    float*    denom  = (float*)(ws + DN_OFF);
    unsigned* EA     = (unsigned*)(ws + EA_OFF);
    bool use_ea = ws_size >= NEED_FULL;

    // zero output + stats (segmax encoded-min is 0)
    hipMemsetAsync(out, 0, (size_t)NN * HD * sizeof(float), stream);
    hipMemsetAsync(ws + SM_OFF, 0, 1600000, stream);

    // node projections
    proj_kernel<<<(NN + 3) / 4, 256, 0, stream>>>(nodes, Ws_k, Ws_b, S, NN);
    proj_kernel<<<(NN + 3) / 4, 256, 0, stream>>>(nodes, Wr_k, Wr_b, R, NN);

    // edge pass 1
    if (use_ea) {
        edge1_kernel<true><<<NE / 4, 256, 0, stream>>>(
            edges, We_k, We_b, attw, attb, senders, receivers, S, R,
            logits, segmax, EA);
    } else {
        edge1_kernel<false><<<NE / 4, 256, 0, stream>>>(
            edges, We_k, We_b, attw, attb, senders, receivers, S, R,
            logits, segmax, nullptr);
    }

    // softmax exp + denom
    edge2_kernel<<<(NE * H + 255) / 256, 256, 0, stream>>>(
        receivers, logits, segmax, denom);

    // aggregation
    if (use_ea) {
        edge3_ea_kernel<<<NE / 4, 256, 0, stream>>>(
            receivers, logits, denom, EA, out);
    } else {
        edge3_rc_kernel<<<NE / 4, 256, 0, stream>>>(
            edges, We_k, We_b, senders, receivers, S, logits, denom, out);
    }
}

// Round 2
// 1260.731 us; speedup vs baseline: 4.0105x; 4.0105x over previous
//
#include <hip/hip_runtime.h>
#include <hip/hip_bf16.h>

#define NN 50000
#define NE 800000
#define F 128     // input feature dim (= K)
#define HD 128    // output dim = H*DH (= N)
#define H 4

typedef __attribute__((ext_vector_type(4))) float f32x4;
typedef __attribute__((ext_vector_type(8))) __bf16 bf16x8;

// ---------- helpers ----------

// order-preserving float<->uint encoding for atomicMax on signed floats
__device__ __forceinline__ unsigned enc_f(float x) {
    unsigned b = __float_as_uint(x);
    return (b & 0x80000000u) ? ~b : (b | 0x80000000u);
}
__device__ __forceinline__ float dec_f(unsigned u) {
    return (u & 0x80000000u) ? __uint_as_float(u ^ 0x80000000u)
                             : __uint_as_float(~u);
}

// mish(x) = x * tanh(softplus(x)) = x * (u-1)/(u+1), u = (1+e^x)^2
__device__ __forceinline__ float mish_f(float x) {
    if (x > 30.f) return x;
    float t = __expf(x);
    float u = 1.f + t;
    u = u * u;
    return x * (u - 1.f) * __builtin_amdgcn_rcpf(u + 1.f);
}

// round-to-nearest-even f32 -> bf16 (uint16 in low bits)
__device__ __forceinline__ unsigned f32_to_bf16(float x) {
    unsigned u = __float_as_uint(x);
    u += 0x7FFFu + ((u >> 16) & 1u);
    return u >> 16;
}
__device__ __forceinline__ float bf16lo_to_f32(unsigned p) {
    return __uint_as_float((p & 0xFFFFu) << 16);
}
__device__ __forceinline__ float bf16hi_to_f32(unsigned p) {
    return __uint_as_float(p & 0xFFFF0000u);
}

// ---------- fused 128-tile MFMA GEMM ----------
// Y128 = X[M x 128] @ W[128 x 128] + bias, then either
//   MODE 0: write f32 Y row-major
//   MODE 1: EA = Y + S[senders]; store EA bf16-packed; logits/segmax from
//           mish(EA + R[receivers]) . attw
template <int MODE>
__global__ __launch_bounds__(256) void gemm_fused(
    const float* __restrict__ X, const float* __restrict__ W,
    const float* __restrict__ bias, int M,
    float* __restrict__ Y,
    const float* __restrict__ attw, const float* __restrict__ attb,
    const int* __restrict__ senders, const int* __restrict__ receivers,
    const float* __restrict__ S, const float* __restrict__ R,
    unsigned* __restrict__ EA, float* __restrict__ logits,
    unsigned* __restrict__ segmax)
{
    __shared__ __align__(16) char ldsb[65536];
    const int t = threadIdx.x;
    const int lane = t & 63;
    const int wid = t >> 6;
    const size_t rowbase = (size_t)blockIdx.x * 128;

    // ---- stage A: X rows -> bf16, XOR-swizzled [row][k] ----
    #pragma unroll
    for (int i = 0; i < 8; ++i) {
        int c = i * 256 + t;          // 2048 16B-chunks
        int row = c >> 4;
        int cc  = c & 15;             // 16B chunk = 8 k's
        size_t e = rowbase + row;
        uint4 p = make_uint4(0, 0, 0, 0);
        if (e < (size_t)M) {
            const float4* src = (const float4*)(X + e * F + cc * 8);
            float4 f0 = src[0], f1 = src[1];
            p.x = f32_to_bf16(f0.x) | (f32_to_bf16(f0.y) << 16);
            p.y = f32_to_bf16(f0.z) | (f32_to_bf16(f0.w) << 16);
            p.z = f32_to_bf16(f1.x) | (f32_to_bf16(f1.y) << 16);
            p.w = f32_to_bf16(f1.z) | (f32_to_bf16(f1.w) << 16);
        }
        unsigned byte = (unsigned)(row * 256 + cc * 16);
        byte ^= (unsigned)((row & 7) << 4);
        *(uint4*)(ldsb + byte) = p;
    }
    // ---- stage B transposed: sBt[n][k] bf16, same swizzle ----
    #pragma unroll
    for (int i = 0; i < 64; ++i) {
        int idx = i * 256 + t;        // 16384 elements, coalesced read
        int k = idx >> 7, n = idx & 127;
        unsigned short v = (unsigned short)f32_to_bf16(W[idx]);
        unsigned byte = (unsigned)(n * 256 + k * 2);
        byte ^= (unsigned)((n & 7) << 4);
        *(unsigned short*)(ldsb + 32768 + byte) = v;
    }

    // bias into accumulators (per output column)
    const int wr = wid >> 1, wc = wid & 1;
    const int l15 = lane & 15, lgp = lane >> 4;
    f32x4 acc[4][4];
    #pragma unroll
    for (int n = 0; n < 4; ++n) {
        float bv = bias[wc * 64 + n * 16 + l15];
        #pragma unroll
        for (int m = 0; m < 4; ++m) {
            acc[m][n][0] = bv; acc[m][n][1] = bv;
            acc[m][n][2] = bv; acc[m][n][3] = bv;
        }
    }
    __syncthreads();

    // ---- MFMA main: 4 ksteps x 16 fragments ----
    #pragma unroll
    for (int ks = 0; ks < 4; ++ks) {
        const int kb = ks * 64 + lgp * 16;   // byte offset of this lane's 8-k chunk
        bf16x8 af[4], bfr[4];
        #pragma unroll
        for (int m = 0; m < 4; ++m) {
            int row = wr * 64 + m * 16 + l15;
            unsigned byte = ((unsigned)(row * 256 + kb)) ^ ((row & 7) << 4);
            af[m] = *(const bf16x8*)(ldsb + byte);
        }
        #pragma unroll
        for (int n = 0; n < 4; ++n) {
            int col = wc * 64 + n * 16 + l15;
            unsigned byte = ((unsigned)(col * 256 + kb)) ^ ((col & 7) << 4);
            bfr[n] = *(const bf16x8*)(ldsb + 32768 + byte);
        }
        #pragma unroll
        for (int m = 0; m < 4; ++m)
            #pragma unroll
            for (int n = 0; n < 4; ++n)
                acc[m][n] = __builtin_amdgcn_mfma_f32_16x16x32_bf16(
                    af[m], bfr[n], acc[m][n], 0, 0, 0);
    }
    __syncthreads();

    // ---- acc -> sC f32 [128][128] ----
    float* sC = (float*)ldsb;
    #pragma unroll
    for (int m = 0; m < 4; ++m) {
        int rbase = wr * 64 + m * 16 + lgp * 4;
        #pragma unroll
        for (int n = 0; n < 4; ++n) {
            int col = wc * 64 + n * 16 + l15;
            #pragma unroll
            for (int j = 0; j < 4; ++j)
                sC[(rbase + j) * 128 + col] = acc[m][n][j];
        }
    }
    __syncthreads();

    // ---- row-parallel tail: wave handles 32 rows ----
    if (MODE == 0) {
        for (int rr = 0; rr < 32; ++rr) {
            int row = wid * 32 + rr;
            size_t e = rowbase + row;
            if (e >= (size_t)M) continue;
            float2 xe = ((const float2*)sC)[row * 64 + lane];
            ((float2*)(Y + e * HD))[lane] = xe;
        }
    } else {
        float2 aw = ((const float2*)attw)[l15];
        float ab0 = attb[0];
        for (int rr = 0; rr < 32; ++rr) {
            int row = wid * 32 + rr;
            size_t e = rowbase + row;
            if (e >= (size_t)M) continue;
            int snd = senders[e];
            int rcv = receivers[e];
            float2 xe = ((const float2*)sC)[row * 64 + lane];
            float2 s2 = ((const float2*)(S + (size_t)snd * HD))[lane];
            float eax = xe.x + s2.x, eay = xe.y + s2.y;
            EA[e * 64 + lane] = f32_to_bf16(eax) | (f32_to_bf16(eay) << 16);
            float2 r2 = ((const float2*)(R + (size_t)rcv * HD))[lane];
            float part = mish_f(eax + r2.x) * aw.x + mish_f(eay + r2.y) * aw.y;
            part += __shfl_xor(part, 1);
            part += __shfl_xor(part, 2);
            part += __shfl_xor(part, 4);
            part += __shfl_xor(part, 8);
            if (l15 == 0) {
                float lgt = part + ab0;
                logits[e * 4 + lgp] = lgt;
                atomicMax(segmax + (size_t)rcv * 4 + lgp, enc_f(lgt));
            }
        }
    }
}

// ---------- K4: exp + denom ----------
__global__ __launch_bounds__(256) void edge2_kernel(
    const int* __restrict__ receivers, float* __restrict__ logits,
    const unsigned* __restrict__ segmax, float* __restrict__ denom)
{
    int i = blockIdx.x * 256 + threadIdx.x;
    if (i >= NE * H) return;
    int e = i >> 2, h = i & 3;
    int rcv = receivers[e];
    float m = dec_f(segmax[(size_t)rcv * 4 + h]);
    float w = expf(logits[i] - m);
    logits[i] = w;
    atomicAdd(denom + (size_t)rcv * 4 + h, w);
}

// ---------- K5: aggregate from stored bf16 e_att ----------
__global__ __launch_bounds__(256) void edge3_ea_kernel(
    const int* __restrict__ receivers, const float* __restrict__ wbuf,
    const float* __restrict__ denom, const unsigned* __restrict__ EA,
    float* __restrict__ out)
{
    int lane = threadIdx.x & 63;
    int e = blockIdx.x * 4 + (threadIdx.x >> 6);
    if (e >= NE) return;
    int rcv = receivers[e];
    int h = lane >> 4;
    float w  = wbuf[(size_t)e * 4 + h];
    float dn = denom[(size_t)rcv * 4 + h];
    float c = w / dn;
    unsigned p = EA[(size_t)e * 64 + lane];
    float a = bf16lo_to_f32(p), b = bf16hi_to_f32(p);
    float* dst = out + (size_t)rcv * HD + 2 * lane;
    atomicAdd(dst, c * a);
    atomicAdd(dst + 1, c * b);
}

// ---------- host ----------
extern "C" void kernel_launch(void* const* d_in, const int* in_sizes, int n_in,
                              void* d_out, int out_size, void* d_ws, size_t ws_size,
                              hipStream_t stream) {
    const float* nodes = (const float*)d_in[0];
    const float* edges = (const float*)d_in[1];
    const float* Ws_k  = (const float*)d_in[2];
    const float* Ws_b  = (const float*)d_in[3];
    const float* Wr_k  = (const float*)d_in[4];
    const float* Wr_b  = (const float*)d_in[5];
    const float* We_k  = (const float*)d_in[6];
    const float* We_b  = (const float*)d_in[7];
    const float* attw  = (const float*)d_in[8];
    const float* attb  = (const float*)d_in[9];
    const int* senders   = (const int*)d_in[10];
    const int* receivers = (const int*)d_in[11];
    float* out = (float*)d_out;

    char* ws = (char*)d_ws;
    const size_t S_OFF   = 0;                    // 25,600,000
    const size_t R_OFF   = 25600000;             // 25,600,000
    const size_t LG_OFF  = 51200000;             // 12,800,000
    const size_t SM_OFF  = 64000000;             // segmax 800,000
    const size_t DN_OFF  = 64800000;             // denom  800,000
    const size_t EA_OFF  = 65600000;             // e_att bf16 204,800,000

    float*    S      = (float*)(ws + S_OFF);
    float*    Rr     = (float*)(ws + R_OFF);
    float*    logits = (float*)(ws + LG_OFF);
    unsigned* segmax = (unsigned*)(ws + SM_OFF);
    float*    denom  = (float*)(ws + DN_OFF);
    unsigned* EA     = (unsigned*)(ws + EA_OFF);
    (void)DN_OFF; (void)ws_size;

    hipMemsetAsync(out, 0, (size_t)NN * HD * sizeof(float), stream);
    hipMemsetAsync(ws + SM_OFF, 0, 1600000, stream);  // segmax + denom

    // node projections S = nodes@Ws + b, R = nodes@Wr + b
    gemm_fused<0><<<(NN + 127) / 128, 256, 0, stream>>>(
        nodes, Ws_k, Ws_b, NN, S,
        nullptr, nullptr, nullptr, nullptr, nullptr, nullptr,
        nullptr, nullptr, nullptr);
    gemm_fused<0><<<(NN + 127) / 128, 256, 0, stream>>>(
        nodes, Wr_k, Wr_b, NN, Rr,
        nullptr, nullptr, nullptr, nullptr, nullptr, nullptr,
        nullptr, nullptr, nullptr);

    // edge pass: EA + logits + segmax
    gemm_fused<1><<<NE / 128, 256, 0, stream>>>(
        edges, We_k, We_b, NE, nullptr,
        attw, attb, senders, receivers, S, Rr,
        EA, logits, segmax);

    // softmax exp + denom
    edge2_kernel<<<(NE * H + 255) / 256, 256, 0, stream>>>(
        receivers, logits, segmax, denom);

    // aggregation
    edge3_ea_kernel<<<NE / 4, 256, 0, stream>>>(
        receivers, logits, denom, EA, out);
}

// Round 3
// 799.472 us; speedup vs baseline: 6.3244x; 1.5770x over previous
//
#include <hip/hip_runtime.h>
#include <hip/hip_bf16.h>

#define NN 50000
#define NE 800000
#define F 128     // input feature dim (= K)
#define HD 128    // output dim = H*DH (= N)
#define H 4

typedef __attribute__((ext_vector_type(4))) float f32x4;
typedef __attribute__((ext_vector_type(8))) __bf16 bf16x8;

// ---------- helpers ----------

// mish(x) = x * tanh(softplus(x)) = x * (u-1)/(u+1), u = (1+e^x)^2
__device__ __forceinline__ float mish_f(float x) {
    if (x > 30.f) return x;
    float t = __expf(x);
    float u = 1.f + t;
    u = u * u;
    return x * (u - 1.f) * __builtin_amdgcn_rcpf(u + 1.f);
}

// round-to-nearest-even f32 -> bf16 (uint16 in low bits)
__device__ __forceinline__ unsigned f32_to_bf16(float x) {
    unsigned u = __float_as_uint(x);
    u += 0x7FFFu + ((u >> 16) & 1u);
    return u >> 16;
}
__device__ __forceinline__ float bf16lo_to_f32(unsigned p) {
    return __uint_as_float((p & 0xFFFFu) << 16);
}
__device__ __forceinline__ float bf16hi_to_f32(unsigned p) {
    return __uint_as_float(p & 0xFFFF0000u);
}

// ---------- fused 128-tile MFMA GEMM ----------
// Y128 = X[M x 128] @ W[128 x 128] + bias, then either
//   MODE 0: write f32 Y row-major
//   MODE 1: EA = Y + S[senders]; store EA bf16-packed; write logits =
//           mish(EA + R[receivers]) . attw + attb   (no atomics)
template <int MODE>
__global__ __launch_bounds__(256) void gemm_fused(
    const float* __restrict__ X, const float* __restrict__ W,
    const float* __restrict__ bias, int M,
    float* __restrict__ Y,
    const float* __restrict__ attw, const float* __restrict__ attb,
    const int* __restrict__ senders, const int* __restrict__ receivers,
    const float* __restrict__ S, const float* __restrict__ R,
    unsigned* __restrict__ EA, float* __restrict__ logits)
{
    __shared__ __align__(16) char ldsb[65536];
    const int t = threadIdx.x;
    const int lane = t & 63;
    const int wid = t >> 6;
    const size_t rowbase = (size_t)blockIdx.x * 128;

    // ---- stage A: X rows -> bf16, XOR-swizzled [row][k] ----
    #pragma unroll
    for (int i = 0; i < 8; ++i) {
        int c = i * 256 + t;          // 2048 16B-chunks
        int row = c >> 4;
        int cc  = c & 15;             // 16B chunk = 8 k's
        size_t e = rowbase + row;
        uint4 p = make_uint4(0, 0, 0, 0);
        if (e < (size_t)M) {
            const float4* src = (const float4*)(X + e * F + cc * 8);
            float4 f0 = src[0], f1 = src[1];
            p.x = f32_to_bf16(f0.x) | (f32_to_bf16(f0.y) << 16);
            p.y = f32_to_bf16(f0.z) | (f32_to_bf16(f0.w) << 16);
            p.z = f32_to_bf16(f1.x) | (f32_to_bf16(f1.y) << 16);
            p.w = f32_to_bf16(f1.z) | (f32_to_bf16(f1.w) << 16);
        }
        unsigned byte = (unsigned)(row * 256 + cc * 16);
        byte ^= (unsigned)((row & 7) << 4);
        *(uint4*)(ldsb + byte) = p;
    }
    // ---- stage B transposed: sBt[n][k] bf16, same swizzle ----
    #pragma unroll
    for (int i = 0; i < 64; ++i) {
        int idx = i * 256 + t;        // 16384 elements, coalesced read
        int k = idx >> 7, n = idx & 127;
        unsigned short v = (unsigned short)f32_to_bf16(W[idx]);
        unsigned byte = (unsigned)(n * 256 + k * 2);
        byte ^= (unsigned)((n & 7) << 4);
        *(unsigned short*)(ldsb + 32768 + byte) = v;
    }

    // bias into accumulators (per output column)
    const int wr = wid >> 1, wc = wid & 1;
    const int l15 = lane & 15, lgp = lane >> 4;
    f32x4 acc[4][4];
    #pragma unroll
    for (int n = 0; n < 4; ++n) {
        float bv = bias[wc * 64 + n * 16 + l15];
        #pragma unroll
        for (int m = 0; m < 4; ++m) {
            acc[m][n][0] = bv; acc[m][n][1] = bv;
            acc[m][n][2] = bv; acc[m][n][3] = bv;
        }
    }
    __syncthreads();

    // ---- MFMA main: 4 ksteps x 16 fragments ----
    #pragma unroll
    for (int ks = 0; ks < 4; ++ks) {
        const int kb = ks * 64 + lgp * 16;   // byte offset of this lane's 8-k chunk
        bf16x8 af[4], bfr[4];
        #pragma unroll
        for (int m = 0; m < 4; ++m) {
            int row = wr * 64 + m * 16 + l15;
            unsigned byte = ((unsigned)(row * 256 + kb)) ^ ((row & 7) << 4);
            af[m] = *(const bf16x8*)(ldsb + byte);
        }
        #pragma unroll
        for (int n = 0; n < 4; ++n) {
            int col = wc * 64 + n * 16 + l15;
            unsigned byte = ((unsigned)(col * 256 + kb)) ^ ((col & 7) << 4);
            bfr[n] = *(const bf16x8*)(ldsb + 32768 + byte);
        }
        #pragma unroll
        for (int m = 0; m < 4; ++m)
            #pragma unroll
            for (int n = 0; n < 4; ++n)
                acc[m][n] = __builtin_amdgcn_mfma_f32_16x16x32_bf16(
                    af[m], bfr[n], acc[m][n], 0, 0, 0);
    }
    __syncthreads();

    // ---- acc -> sC f32 [128][128] ----
    float* sC = (float*)ldsb;
    #pragma unroll
    for (int m = 0; m < 4; ++m) {
        int rbase = wr * 64 + m * 16 + lgp * 4;
        #pragma unroll
        for (int n = 0; n < 4; ++n) {
            int col = wc * 64 + n * 16 + l15;
            #pragma unroll
            for (int j = 0; j < 4; ++j)
                sC[(rbase + j) * 128 + col] = acc[m][n][j];
        }
    }
    __syncthreads();

    // ---- row-parallel tail: wave handles 32 rows ----
    if (MODE == 0) {
        for (int rr = 0; rr < 32; ++rr) {
            int row = wid * 32 + rr;
            size_t e = rowbase + row;
            if (e >= (size_t)M) continue;
            float2 xe = ((const float2*)sC)[row * 64 + lane];
            ((float2*)(Y + e * HD))[lane] = xe;
        }
    } else {
        float2 aw = ((const float2*)attw)[l15];
        float ab0 = attb[0];
        for (int rr = 0; rr < 32; ++rr) {
            int row = wid * 32 + rr;
            size_t e = rowbase + row;
            if (e >= (size_t)M) continue;
            int snd = senders[e];
            int rcv = receivers[e];
            float2 xe = ((const float2*)sC)[row * 64 + lane];
            float2 s2 = ((const float2*)(S + (size_t)snd * HD))[lane];
            float eax = xe.x + s2.x, eay = xe.y + s2.y;
            EA[e * 64 + lane] = f32_to_bf16(eax) | (f32_to_bf16(eay) << 16);
            float2 r2 = ((const float2*)(R + (size_t)rcv * HD))[lane];
            float part = mish_f(eax + r2.x) * aw.x + mish_f(eay + r2.y) * aw.y;
            part += __shfl_xor(part, 1);
            part += __shfl_xor(part, 2);
            part += __shfl_xor(part, 4);
            part += __shfl_xor(part, 8);
            if (l15 == 0) logits[e * 4 + lgp] = part + ab0;
        }
    }
}

// ---------- CSR build: histogram ----------
__global__ __launch_bounds__(256) void hist_kernel(
    const int* __restrict__ receivers, unsigned* __restrict__ cnt)
{
    int i = blockIdx.x * 256 + threadIdx.x;
    if (i < NE) atomicAdd(&cnt[receivers[i]], 1u);
}

// ---------- CSR build: single-block exclusive scan ----------
__global__ __launch_bounds__(1024) void scan_kernel(
    const unsigned* __restrict__ cnt, unsigned* __restrict__ rowptr)
{
    __shared__ unsigned part[1024];
    const int t = threadIdx.x;
    const int C = (NN + 1023) / 1024;   // 49
    int base = t * C;
    unsigned s = 0;
    for (int i = 0; i < C; ++i) {
        int idx = base + i;
        if (idx < NN) s += cnt[idx];
    }
    part[t] = s;
    __syncthreads();
    for (int off = 1; off < 1024; off <<= 1) {
        unsigned v = (t >= off) ? part[t - off] : 0u;
        __syncthreads();
        if (t >= off) part[t] += v;
        __syncthreads();
    }
    unsigned run = part[t] - s;   // exclusive base for this thread's chunk
    for (int i = 0; i < C; ++i) {
        int idx = base + i;
        if (idx < NN) { rowptr[idx] = run; run += cnt[idx]; }
    }
    if (t == 1023) rowptr[NN] = run;
}

// ---------- CSR build: scatter permutation ----------
__global__ __launch_bounds__(256) void scatter_kernel(
    const int* __restrict__ receivers, const unsigned* __restrict__ rowptr,
    unsigned* __restrict__ cnt2, unsigned* __restrict__ perm)
{
    int i = blockIdx.x * 256 + threadIdx.x;
    if (i >= NE) return;
    int r = receivers[i];
    unsigned pos = rowptr[r] + atomicAdd(&cnt2[r], 1u);
    perm[pos] = (unsigned)i;
}

// ---------- fused segment softmax + aggregate (one wave per receiver) ----------
__global__ __launch_bounds__(256) void agg_kernel(
    const unsigned* __restrict__ rowptr, const unsigned* __restrict__ perm,
    const float* __restrict__ logits, const unsigned* __restrict__ EA,
    float* __restrict__ out)
{
    const int lane = threadIdx.x & 63;
    const int r = blockIdx.x * 4 + (threadIdx.x >> 6);
    if (r >= NN) return;
    const unsigned start = rowptr[r], end = rowptr[r + 1];
    float2* dst = (float2*)(out + (size_t)r * HD);
    if (start == end) { dst[lane] = make_float2(0.f, 0.f); return; }

    const int h = lane >> 4;
    const float NEGBIG = -3.402823466e+38f;

    // pass A: per-head max, then exp-sum (wave-parallel over segment)
    float4 mx = make_float4(NEGBIG, NEGBIG, NEGBIG, NEGBIG);
    for (unsigned j = start + lane; j < end; j += 64) {
        unsigned e = perm[j];
        float4 lg = ((const float4*)logits)[e];
        mx.x = fmaxf(mx.x, lg.x); mx.y = fmaxf(mx.y, lg.y);
        mx.z = fmaxf(mx.z, lg.z); mx.w = fmaxf(mx.w, lg.w);
    }
    #pragma unroll
    for (int o = 1; o < 64; o <<= 1) {
        mx.x = fmaxf(mx.x, __shfl_xor(mx.x, o));
        mx.y = fmaxf(mx.y, __shfl_xor(mx.y, o));
        mx.z = fmaxf(mx.z, __shfl_xor(mx.z, o));
        mx.w = fmaxf(mx.w, __shfl_xor(mx.w, o));
    }
    float4 sm = make_float4(0.f, 0.f, 0.f, 0.f);
    for (unsigned j = start + lane; j < end; j += 64) {
        unsigned e = perm[j];
        float4 lg = ((const float4*)logits)[e];
        sm.x += __expf(lg.x - mx.x); sm.y += __expf(lg.y - mx.y);
        sm.z += __expf(lg.z - mx.z); sm.w += __expf(lg.w - mx.w);
    }
    #pragma unroll
    for (int o = 1; o < 64; o <<= 1) {
        sm.x += __shfl_xor(sm.x, o);
        sm.y += __shfl_xor(sm.y, o);
        sm.z += __shfl_xor(sm.z, o);
        sm.w += __shfl_xor(sm.w, o);
    }
    const float mh = (h == 0) ? mx.x : (h == 1) ? mx.y : (h == 2) ? mx.z : mx.w;
    const float sh = (h == 0) ? sm.x : (h == 1) ? sm.y : (h == 2) ? sm.z : sm.w;
    const float rd = 1.f / sh;

    // pass B: weighted accumulate of EA rows
    float2 acc = make_float2(0.f, 0.f);
    for (unsigned j = start; j < end; ++j) {
        unsigned e = perm[j];
        float lg = logits[(size_t)e * 4 + h];
        float c = __expf(lg - mh) * rd;
        unsigned p = EA[(size_t)e * 64 + lane];
        acc.x += c * bf16lo_to_f32(p);
        acc.y += c * bf16hi_to_f32(p);
    }
    dst[lane] = acc;
}

// ---------- host ----------
extern "C" void kernel_launch(void* const* d_in, const int* in_sizes, int n_in,
                              void* d_out, int out_size, void* d_ws, size_t ws_size,
                              hipStream_t stream) {
    const float* nodes = (const float*)d_in[0];
    const float* edges = (const float*)d_in[1];
    const float* Ws_k  = (const float*)d_in[2];
    const float* Ws_b  = (const float*)d_in[3];
    const float* Wr_k  = (const float*)d_in[4];
    const float* Wr_b  = (const float*)d_in[5];
    const float* We_k  = (const float*)d_in[6];
    const float* We_b  = (const float*)d_in[7];
    const float* attw  = (const float*)d_in[8];
    const float* attb  = (const float*)d_in[9];
    const int* senders   = (const int*)d_in[10];
    const int* receivers = (const int*)d_in[11];
    float* out = (float*)d_out;

    char* ws = (char*)d_ws;
    // region 0..25.6e6 holds S during the GEMM phase, then is reused for CSR
    const size_t S_OFF    = 0;            // 25,600,000 (dead after edge GEMM)
    const size_t CNT_OFF  = 0;            // 200,000
    const size_t CNT2_OFF = 200000;       // 200,000
    const size_t RP_OFF   = 400000;       // 200,004
    const size_t PERM_OFF = 700000;       // 3,200,000 (ends 3.9e6 < 25.6e6)
    const size_t R_OFF    = 25600000;     // 25,600,000
    const size_t LG_OFF   = 51200000;     // 12,800,000
    const size_t EA_OFF   = 65600000;     // 204,800,000

    float*    S      = (float*)(ws + S_OFF);
    float*    Rr     = (float*)(ws + R_OFF);
    float*    logits = (float*)(ws + LG_OFF);
    unsigned* cnt    = (unsigned*)(ws + CNT_OFF);
    unsigned* cnt2   = (unsigned*)(ws + CNT2_OFF);
    unsigned* rowptr = (unsigned*)(ws + RP_OFF);
    unsigned* perm   = (unsigned*)(ws + PERM_OFF);
    unsigned* EA     = (unsigned*)(ws + EA_OFF);
    (void)ws_size;

    // node projections S = nodes@Ws + b, R = nodes@Wr + b
    gemm_fused<0><<<(NN + 127) / 128, 256, 0, stream>>>(
        nodes, Ws_k, Ws_b, NN, S,
        nullptr, nullptr, nullptr, nullptr, nullptr, nullptr,
        nullptr, nullptr);
    gemm_fused<0><<<(NN + 127) / 128, 256, 0, stream>>>(
        nodes, Wr_k, Wr_b, NN, Rr,
        nullptr, nullptr, nullptr, nullptr, nullptr, nullptr,
        nullptr, nullptr);

    // edge pass: EA (bf16) + logits
    gemm_fused<1><<<NE / 128, 256, 0, stream>>>(
        edges, We_k, We_b, NE, nullptr,
        attw, attb, senders, receivers, S, Rr,
        EA, logits);

    // CSR build in the (now dead) S region
    hipMemsetAsync(ws + CNT_OFF, 0, 400000, stream);   // cnt + cnt2
    hist_kernel<<<(NE + 255) / 256, 256, 0, stream>>>(receivers, cnt);
    scan_kernel<<<1, 1024, 0, stream>>>(cnt, rowptr);
    scatter_kernel<<<(NE + 255) / 256, 256, 0, stream>>>(receivers, rowptr, cnt2, perm);

    // fused segment softmax + aggregation (writes every output row once)
    agg_kernel<<<(NN + 3) / 4, 256, 0, stream>>>(rowptr, perm, logits, EA, out);
}

// Round 4
// 635.317 us; speedup vs baseline: 7.9585x; 1.2584x over previous
//
#include <hip/hip_runtime.h>
#include <hip/hip_bf16.h>

#define NN 50000
#define NE 800000
#define F 128     // input feature dim (= K)
#define HD 128    // output dim = H*DH (= N)
#define H 4

typedef __attribute__((ext_vector_type(4))) float f32x4;
typedef __attribute__((ext_vector_type(8))) __bf16 bf16x8;

// ---------- helpers ----------

// mish(x) = x * tanh(softplus(x)) = x * (u-1)/(u+1), u = (1+e^x)^2
__device__ __forceinline__ float mish_f(float x) {
    if (x > 30.f) return x;
    float t = __expf(x);
    float u = 1.f + t;
    u = u * u;
    return x * (u - 1.f) * __builtin_amdgcn_rcpf(u + 1.f);
}

// round-to-nearest-even f32 -> bf16 (uint16 in low bits)
__device__ __forceinline__ unsigned f32_to_bf16(float x) {
    unsigned u = __float_as_uint(x);
    u += 0x7FFFu + ((u >> 16) & 1u);
    return u >> 16;
}
__device__ __forceinline__ float bf16lo_to_f32(unsigned p) {
    return __uint_as_float((p & 0xFFFFu) << 16);
}
__device__ __forceinline__ float bf16hi_to_f32(unsigned p) {
    return __uint_as_float(p & 0xFFFF0000u);
}

// ---------- prep: W f32[128k x 128n] -> bf16 fragment-ordered ----------
// chunk c (16B): fn=c>>8, ks=(c>>6)&3, lane=c&63 (lgp=lane>>4,l15=lane&15)
// holds W[k0..k0+7][col], col=fn*16+l15, k0=ks*32+lgp*8
__global__ __launch_bounds__(256) void prep_w(
    const float* __restrict__ W0, const float* __restrict__ W1,
    const float* __restrict__ W2, uint4* __restrict__ O)
{
    int b = blockIdx.x;
    const float* W = (b == 0) ? W0 : (b == 1) ? W1 : W2;
    uint4* out = O + b * 2048;
    for (int c = threadIdx.x; c < 2048; c += 256) {
        int fn = c >> 8, ks = (c >> 6) & 3, lane = c & 63;
        int lgp = lane >> 4, l15 = lane & 15;
        int col = fn * 16 + l15, k0 = ks * 32 + lgp * 8;
        unsigned u[4];
        #pragma unroll
        for (int i = 0; i < 4; ++i) {
            float a = W[(k0 + 2 * i) * 128 + col];
            float bb = W[(k0 + 2 * i + 1) * 128 + col];
            u[i] = f32_to_bf16(a) | (f32_to_bf16(bb) << 16);
        }
        out[c] = make_uint4(u[0], u[1], u[2], u[3]);
    }
}

// ---------- fused 128-tile MFMA GEMM, B from fragment-ordered global ----------
// MODE 0: Y[e,:] = X@W + b (f32 row-major)
// MODE 1: EA = Y + S[snd] stored bf16 fragment-permuted (256B/edge);
//         logits[e][h] = mish(EA + R[rcv]) . attw + attb
template <int MODE>
__global__ __launch_bounds__(256, 4) void gemm2(
    const float* __restrict__ X, const bf16x8* __restrict__ Wf,
    const float* __restrict__ bias, int M,
    float* __restrict__ Y,
    const float* __restrict__ attw, const float* __restrict__ attb,
    const int* __restrict__ senders, const int* __restrict__ receivers,
    const float* __restrict__ S, const float* __restrict__ R,
    uint2* __restrict__ EA, float* __restrict__ logits)
{
    __shared__ __align__(16) char ldsA[32768];
    __shared__ float sPart[128][4];
    const int t = threadIdx.x;
    const int lane = t & 63;
    const int wid = t >> 6;
    const size_t rowbase = (size_t)blockIdx.x * 128;

    // ---- stage A: X rows -> bf16, XOR-swizzled [row][k] (32KB) ----
    #pragma unroll
    for (int i = 0; i < 8; ++i) {
        int c = i * 256 + t;          // 2048 16B-chunks
        int row = c >> 4;
        int cc  = c & 15;             // 16B chunk = 8 k's
        size_t e = rowbase + row;
        uint4 p = make_uint4(0, 0, 0, 0);
        if (e < (size_t)M) {
            const float4* src = (const float4*)(X + e * F + cc * 8);
            float4 f0 = src[0], f1 = src[1];
            p.x = f32_to_bf16(f0.x) | (f32_to_bf16(f0.y) << 16);
            p.y = f32_to_bf16(f0.z) | (f32_to_bf16(f0.w) << 16);
            p.z = f32_to_bf16(f1.x) | (f32_to_bf16(f1.y) << 16);
            p.w = f32_to_bf16(f1.z) | (f32_to_bf16(f1.w) << 16);
        }
        unsigned byte = (unsigned)(row * 256 + cc * 16);
        byte ^= (unsigned)((row & 7) << 4);
        *(uint4*)(ldsA + byte) = p;
    }

    const int wr = wid >> 1, wc = wid & 1;
    const int l15 = lane & 15, lgp = lane >> 4;
    f32x4 acc[4][4];
    #pragma unroll
    for (int n = 0; n < 4; ++n) {
        float bv = bias[wc * 64 + n * 16 + l15];
        #pragma unroll
        for (int m = 0; m < 4; ++m) {
            acc[m][n][0] = bv; acc[m][n][1] = bv;
            acc[m][n][2] = bv; acc[m][n][3] = bv;
        }
    }
    __syncthreads();

    // ---- MFMA main: A from LDS, B straight from global (L1/L2-hot) ----
    #pragma unroll
    for (int ks = 0; ks < 4; ++ks) {
        const int kb = ks * 64 + lgp * 16;
        bf16x8 af[4], bfr[4];
        #pragma unroll
        for (int m = 0; m < 4; ++m) {
            int row = wr * 64 + m * 16 + l15;
            unsigned byte = ((unsigned)(row * 256 + kb)) ^ ((row & 7) << 4);
            af[m] = *(const bf16x8*)(ldsA + byte);
        }
        #pragma unroll
        for (int n = 0; n < 4; ++n)
            bfr[n] = Wf[((wc * 4 + n) * 4 + ks) * 64 + lane];
        #pragma unroll
        for (int m = 0; m < 4; ++m)
            #pragma unroll
            for (int n = 0; n < 4; ++n)
                acc[m][n] = __builtin_amdgcn_mfma_f32_16x16x32_bf16(
                    af[m], bfr[n], acc[m][n], 0, 0, 0);
    }

    // ---- tail: in-register, no sC round-trip ----
    if (MODE == 0) {
        #pragma unroll
        for (int m = 0; m < 4; ++m)
            #pragma unroll
            for (int j = 0; j < 4; ++j) {
                int row = wr * 64 + m * 16 + lgp * 4 + j;
                size_t e = rowbase + row;
                if (e >= (size_t)M) continue;
                float* dst = Y + e * HD + wc * 64 + l15;
                #pragma unroll
                for (int n = 0; n < 4; ++n)
                    dst[n * 16] = acc[m][n][j];
            }
    } else {
        const float aw0 = attw[l15];
        const float aw1 = attw[l15 + 16];
        const float ab0 = attb[0];
        #pragma unroll
        for (int m = 0; m < 4; ++m) {
            #pragma unroll
            for (int j = 0; j < 4; ++j) {
                int row = wr * 64 + m * 16 + lgp * 4 + j;
                size_t e = rowbase + row;
                int snd = senders[e];
                int rcv = receivers[e];
                const float* Srow = S + (size_t)snd * HD + wc * 64 + l15;
                const float* Rrow = R + (size_t)rcv * HD + wc * 64 + l15;
                float ea0 = acc[m][0][j] + Srow[0];
                float ea1 = acc[m][1][j] + Srow[16];
                float ea2 = acc[m][2][j] + Srow[32];
                float ea3 = acc[m][3][j] + Srow[48];
                float p0 = mish_f(ea0 + Rrow[0])  * aw0
                         + mish_f(ea1 + Rrow[16]) * aw1;
                float p1 = mish_f(ea2 + Rrow[32]) * aw0
                         + mish_f(ea3 + Rrow[48]) * aw1;
                // EA fragment-permuted: ushort idx = wc*64 + l15*4 + n
                uint2 pk;
                pk.x = f32_to_bf16(ea0) | (f32_to_bf16(ea1) << 16);
                pk.y = f32_to_bf16(ea2) | (f32_to_bf16(ea3) << 16);
                EA[e * 32 + wc * 16 + l15] = pk;
                p0 += __shfl_xor(p0, 1); p1 += __shfl_xor(p1, 1);
                p0 += __shfl_xor(p0, 2); p1 += __shfl_xor(p1, 2);
                p0 += __shfl_xor(p0, 4); p1 += __shfl_xor(p1, 4);
                p0 += __shfl_xor(p0, 8); p1 += __shfl_xor(p1, 8);
                if (l15 == 0) {
                    sPart[row][wc * 2 + 0] = p0;
                    sPart[row][wc * 2 + 1] = p1;
                }
            }
        }
        __syncthreads();
        if (t < 128) {
            size_t e = rowbase + t;
            float4 lg;
            lg.x = sPart[t][0] + ab0;
            lg.y = sPart[t][1] + ab0;
            lg.z = sPart[t][2] + ab0;
            lg.w = sPart[t][3] + ab0;
            ((float4*)logits)[e] = lg;
        }
    }
}

// ---------- CSR build: histogram ----------
__global__ __launch_bounds__(256) void hist_kernel(
    const int* __restrict__ receivers, unsigned* __restrict__ cnt)
{
    int i = blockIdx.x * 256 + threadIdx.x;
    if (i < NE) atomicAdd(&cnt[receivers[i]], 1u);
}

// ---------- CSR build: single-block exclusive scan ----------
__global__ __launch_bounds__(1024) void scan_kernel(
    const unsigned* __restrict__ cnt, unsigned* __restrict__ rowptr)
{
    __shared__ unsigned part[1024];
    const int t = threadIdx.x;
    const int C = (NN + 1023) / 1024;   // 49
    int base = t * C;
    unsigned s = 0;
    for (int i = 0; i < C; ++i) {
        int idx = base + i;
        if (idx < NN) s += cnt[idx];
    }
    part[t] = s;
    __syncthreads();
    for (int off = 1; off < 1024; off <<= 1) {
        unsigned v = (t >= off) ? part[t - off] : 0u;
        __syncthreads();
        if (t >= off) part[t] += v;
        __syncthreads();
    }
    unsigned run = part[t] - s;
    for (int i = 0; i < C; ++i) {
        int idx = base + i;
        if (idx < NN) { rowptr[idx] = run; run += cnt[idx]; }
    }
    if (t == 1023) rowptr[NN] = run;
}

// ---------- CSR build: scatter permutation ----------
__global__ __launch_bounds__(256) void scatter_kernel(
    const int* __restrict__ receivers, const unsigned* __restrict__ rowptr,
    unsigned* __restrict__ cnt2, unsigned* __restrict__ perm)
{
    int i = blockIdx.x * 256 + threadIdx.x;
    if (i >= NE) return;
    int r = receivers[i];
    unsigned pos = rowptr[r] + atomicAdd(&cnt2[r], 1u);
    perm[pos] = (unsigned)i;
}

// ---------- fused segment softmax + aggregate (one wave per receiver) ----------
__global__ __launch_bounds__(256) void agg_kernel(
    const unsigned* __restrict__ rowptr, const unsigned* __restrict__ perm,
    const float* __restrict__ logits, const unsigned* __restrict__ EA,
    float* __restrict__ out)
{
    const int lane = threadIdx.x & 63;
    const int r = blockIdx.x * 4 + (threadIdx.x >> 6);
    if (r >= NN) return;
    const unsigned start = rowptr[r], end = rowptr[r + 1];
    if (start == end) {
        ((float2*)(out + (size_t)r * HD))[lane] = make_float2(0.f, 0.f);
        return;
    }

    // fragment-permuted EA: uint at index `lane` holds cols c0, c0+16
    const int h  = (lane >> 5) * 2 + (lane & 1);
    const int c0 = (lane >> 5) * 64 + (lane & 1) * 32 + ((lane >> 1) & 15);
    const float NEGBIG = -3.402823466e+38f;

    float4 mx = make_float4(NEGBIG, NEGBIG, NEGBIG, NEGBIG);
    for (unsigned j = start + lane; j < end; j += 64) {
        unsigned e = perm[j];
        float4 lg = ((const float4*)logits)[e];
        mx.x = fmaxf(mx.x, lg.x); mx.y = fmaxf(mx.y, lg.y);
        mx.z = fmaxf(mx.z, lg.z); mx.w = fmaxf(mx.w, lg.w);
    }
    #pragma unroll
    for (int o = 1; o < 64; o <<= 1) {
        mx.x = fmaxf(mx.x, __shfl_xor(mx.x, o));
        mx.y = fmaxf(mx.y, __shfl_xor(mx.y, o));
        mx.z = fmaxf(mx.z, __shfl_xor(mx.z, o));
        mx.w = fmaxf(mx.w, __shfl_xor(mx.w, o));
    }
    float4 sm = make_float4(0.f, 0.f, 0.f, 0.f);
    for (unsigned j = start + lane; j < end; j += 64) {
        unsigned e = perm[j];
        float4 lg = ((const float4*)logits)[e];
        sm.x += __expf(lg.x - mx.x); sm.y += __expf(lg.y - mx.y);
        sm.z += __expf(lg.z - mx.z); sm.w += __expf(lg.w - mx.w);
    }
    #pragma unroll
    for (int o = 1; o < 64; o <<= 1) {
        sm.x += __shfl_xor(sm.x, o);
        sm.y += __shfl_xor(sm.y, o);
        sm.z += __shfl_xor(sm.z, o);
        sm.w += __shfl_xor(sm.w, o);
    }
    const float mh = (h == 0) ? mx.x : (h == 1) ? mx.y : (h == 2) ? mx.z : mx.w;
    const float sh = (h == 0) ? sm.x : (h == 1) ? sm.y : (h == 2) ? sm.z : sm.w;
    const float rd = 1.f / sh;

    float2 acc = make_float2(0.f, 0.f);
    for (unsigned j = start; j < end; ++j) {
        unsigned e = perm[j];
        float lg = logits[(size_t)e * 4 + h];
        float c = __expf(lg - mh) * rd;
        unsigned p = EA[(size_t)e * 64 + lane];
        acc.x += c * bf16lo_to_f32(p);
        acc.y += c * bf16hi_to_f32(p);
    }
    out[(size_t)r * HD + c0]      = acc.x;
    out[(size_t)r * HD + c0 + 16] = acc.y;
}

// ---------- host ----------
extern "C" void kernel_launch(void* const* d_in, const int* in_sizes, int n_in,
                              void* d_out, int out_size, void* d_ws, size_t ws_size,
                              hipStream_t stream) {
    const float* nodes = (const float*)d_in[0];
    const float* edges = (const float*)d_in[1];
    const float* Ws_k  = (const float*)d_in[2];
    const float* Ws_b  = (const float*)d_in[3];
    const float* Wr_k  = (const float*)d_in[4];
    const float* Wr_b  = (const float*)d_in[5];
    const float* We_k  = (const float*)d_in[6];
    const float* We_b  = (const float*)d_in[7];
    const float* attw  = (const float*)d_in[8];
    const float* attb  = (const float*)d_in[9];
    const int* senders   = (const int*)d_in[10];
    const int* receivers = (const int*)d_in[11];
    float* out = (float*)d_out;

    char* ws = (char*)d_ws;
    const size_t S_OFF    = 0;            // 25,600,000 (dead after edge GEMM)
    const size_t CNT_OFF  = 0;            // 200,000
    const size_t CNT2_OFF = 200000;       // 200,000
    const size_t RP_OFF   = 400000;       // 200,004
    const size_t PERM_OFF = 700000;       // 3,200,000
    const size_t R_OFF    = 25600000;     // 25,600,000
    const size_t LG_OFF   = 51200000;     // 12,800,000
    const size_t WF_OFF   = 64000000;     // 98,304 (3 x 32KB bf16 fragment W)
    const size_t EA_OFF   = 65600000;     // 204,800,000

    float*    S      = (float*)(ws + S_OFF);
    float*    Rr     = (float*)(ws + R_OFF);
    float*    logits = (float*)(ws + LG_OFF);
    unsigned* cnt    = (unsigned*)(ws + CNT_OFF);
    unsigned* cnt2   = (unsigned*)(ws + CNT2_OFF);
    unsigned* rowptr = (unsigned*)(ws + RP_OFF);
    unsigned* perm   = (unsigned*)(ws + PERM_OFF);
    uint4*    Wf     = (uint4*)(ws + WF_OFF);
    unsigned* EA     = (unsigned*)(ws + EA_OFF);
    (void)ws_size;

    // weights -> bf16 fragment order (Ws, Wr, We)
    prep_w<<<3, 256, 0, stream>>>(Ws_k, Wr_k, We_k, Wf);

    // node projections
    gemm2<0><<<(NN + 127) / 128, 256, 0, stream>>>(
        nodes, (const bf16x8*)(Wf), Ws_b, NN, S,
        nullptr, nullptr, nullptr, nullptr, nullptr, nullptr,
        nullptr, nullptr);
    gemm2<0><<<(NN + 127) / 128, 256, 0, stream>>>(
        nodes, (const bf16x8*)(Wf + 2048), Wr_b, NN, Rr,
        nullptr, nullptr, nullptr, nullptr, nullptr, nullptr,
        nullptr, nullptr);

    // edge pass: EA (bf16, fragment-permuted) + logits
    gemm2<1><<<NE / 128, 256, 0, stream>>>(
        edges, (const bf16x8*)(Wf + 4096), We_b, NE, nullptr,
        attw, attb, senders, receivers, S, Rr,
        (uint2*)EA, logits);

    // CSR build in the (now dead) S region
    hipMemsetAsync(ws + CNT_OFF, 0, 400000, stream);   // cnt + cnt2
    hist_kernel<<<(NE + 255) / 256, 256, 0, stream>>>(receivers, cnt);
    scan_kernel<<<1, 1024, 0, stream>>>(cnt, rowptr);
    scatter_kernel<<<(NE + 255) / 256, 256, 0, stream>>>(receivers, rowptr, cnt2, perm);

    // fused segment softmax + aggregation
    agg_kernel<<<(NN + 3) / 4, 256, 0, stream>>>(rowptr, perm, logits, EA, out);
}